// Round 2
// baseline (3738.505 us; speedup 1.0000x reference)
//
#include <hip/hip_runtime.h>
#include <hip/hip_bf16.h>
#include <stdint.h>

#define W4   20736           // 12^4 positions (w == W4, no padding)
#define NH   8
#define KD   32
#define HD   64
#define C    512
#define SCALE 0.17677669529663687f   // 1/sqrt(32)

typedef unsigned long long ull;

// ---------------------------------------------------------------------------
// Prep: fold head-summed K weights; build GEMM routing tables.
//   Table A (896 rows): [0,256) q1, [256,768) v, [768,800) ks1-fold, pad.
//   Table B (384 rows): [0,256) q2, [256,288) ks2-fold, pad.
//   Table P (512 rows): proj.
// ---------------------------------------------------------------------------
__global__ __launch_bounds__(256) void prep_kernel(
    const float* qk1_w, const float* qk1_g, const float* qk1_b,
    const float* qk2_w, const float* qk2_g, const float* qk2_b,
    const float* v_w,   const float* v_g,   const float* v_b,
    const float* proj_w,const float* proj_g,const float* proj_b,
    float* ksw1, float* ksw2,
    ull* wpA, ull* opA, int* bsA, float* gA, float* bA,
    ull* wpB, ull* opB, int* bsB, float* gB, float* bB,
    ull* wpP, ull* opP, int* bsP, float* gP, float* bP,
    float* qbuf, float* ks1buf, float* ks2buf,
    float* vdst /* d_out */, float* ybuf /* A1 region */)
{
    int z = blockIdx.x, t = threadIdx.x;
    if (z < 32) {                       // fold ksw1 row d=z : sum_h g*W over k1 channels
        int d = z;
        for (int c = t; c < 512; c += 256) {
            float a = 0.f;
            #pragma unroll
            for (int h = 0; h < 8; h++) {
                int ch = h * 64 + 32 + d;
                a += qk1_g[ch] * qk1_w[ch * 512 + c];
            }
            ksw1[d * 512 + c] = a;
        }
    } else if (z < 64) {                // fold ksw2 row d=z-32
        int d = z - 32;
        for (int c = t; c < 512; c += 256) {
            float a = 0.f;
            #pragma unroll
            for (int h = 0; h < 8; h++) {
                int ch = h * 64 + 32 + d;
                a += qk2_g[ch] * qk2_w[ch * 512 + c];
            }
            ksw2[d * 512 + c] = a;
        }
    } else if (z == 64) {               // table A
        for (int o = t; o < 896; o += 256) {
            ull w; float g, bb; ull op; int bs;
            if (o < 256) {              // q1: ch = n*64 + d (s=0)
                int n = o >> 5, d = o & 31, ch = n * 64 + d;
                w = (ull)(uintptr_t)(qk1_w + (size_t)ch * 512);
                g = qk1_g[ch]; bb = qk1_b[ch];
                op = (ull)(uintptr_t)(qbuf + (size_t)o * W4); bs = 256 * W4;
            } else if (o < 768) {       // v -> d_out
                int c = o - 256;
                w = (ull)(uintptr_t)(v_w + (size_t)c * 512);
                g = v_g[c]; bb = v_b[c];
                op = (ull)(uintptr_t)(vdst + (size_t)c * W4); bs = 512 * W4;
            } else if (o < 800) {       // k1sum (folded)
                int d = o - 768;
                w = (ull)(uintptr_t)(ksw1 + (size_t)d * 512);
                g = 1.f; bb = 0.f;
                #pragma unroll
                for (int h = 0; h < 8; h++) bb += qk1_b[h * 64 + 32 + d];
                op = (ull)(uintptr_t)(ks1buf + (size_t)d * W4); bs = 32 * W4;
            } else {                    // pad (masked by m_valid)
                w = (ull)(uintptr_t)qk1_w; g = 0.f; bb = 0.f;
                op = (ull)(uintptr_t)qbuf; bs = 0;
            }
            wpA[o] = w; gA[o] = g; bA[o] = bb; opA[o] = op; bsA[o] = bs;
        }
    } else if (z == 65) {               // table B
        for (int o = t; o < 384; o += 256) {
            ull w; float g, bb; ull op; int bs;
            if (o < 256) {              // q2
                int n = o >> 5, d = o & 31, ch = n * 64 + d;
                w = (ull)(uintptr_t)(qk2_w + (size_t)ch * 512);
                g = qk2_g[ch]; bb = qk2_b[ch];
                op = (ull)(uintptr_t)(qbuf + (size_t)o * W4); bs = 256 * W4;
            } else if (o < 288) {       // k2sum (folded)
                int d = o - 256;
                w = (ull)(uintptr_t)(ksw2 + (size_t)d * 512);
                g = 1.f; bb = 0.f;
                #pragma unroll
                for (int h = 0; h < 8; h++) bb += qk2_b[h * 64 + 32 + d];
                op = (ull)(uintptr_t)(ks2buf + (size_t)d * W4); bs = 32 * W4;
            } else {
                w = (ull)(uintptr_t)qk2_w; g = 0.f; bb = 0.f;
                op = (ull)(uintptr_t)qbuf; bs = 0;
            }
            wpB[o] = w; gB[o] = g; bB[o] = bb; opB[o] = op; bsB[o] = bs;
        }
    } else {                            // table P (proj)
        for (int o = t; o < 512; o += 256) {
            wpP[o] = (ull)(uintptr_t)(proj_w + (size_t)o * 512);
            gP[o] = proj_g[o]; bP[o] = proj_b[o];
            opP[o] = (ull)(uintptr_t)(vdst + (size_t)o * W4);
            bsP[o] = 512 * W4;
        }
    }
}

// ---------------------------------------------------------------------------
// conv1x1 GEMM: out[o,p] = (sum_c W[o][c]*B[b,c,p])*g[o]+beta[o].
// 128x128 tile, BK=8, 256 threads, 8x8 micro-tile. Per-row routing tables.
// (bit-verified in round 1 analysis)
// ---------------------------------------------------------------------------
__global__ __launch_bounds__(256) void conv1x1_gemm(
    const float* __restrict__ Bmat, long bstrideB,
    const ull* __restrict__ wptr, const ull* __restrict__ outp,
    const int* __restrict__ obstr,
    const float* __restrict__ gtab, const float* __restrict__ btab,
    int K, int m_valid)
{
    __shared__ float As[8][132];
    __shared__ float Bs[8][132];
    const int t  = threadIdx.x;
    const int b  = blockIdx.z;
    const int m0 = blockIdx.y * 128;
    const int n0 = blockIdx.x * 128;
    const int arow = t >> 1,  acb = (t & 1) * 4;
    const int brow = t >> 5,  bcb = (t & 31) * 4;
    const float* wr = (const float*)(uintptr_t)wptr[m0 + arow];
    const float* bp = Bmat + (long)b * bstrideB + (long)brow * W4 + n0 + bcb;
    const int tx = t & 15, ty = t >> 4;
    float acc[8][8];
    #pragma unroll
    for (int i = 0; i < 8; i++)
        #pragma unroll
        for (int j = 0; j < 8; j++) acc[i][j] = 0.f;

    for (int k0 = 0; k0 < K; k0 += 8) {
        float4 av = *(const float4*)(wr + k0 + acb);
        float4 bv = *(const float4*)(bp + (long)k0 * W4);
        __syncthreads();
        As[acb + 0][arow] = av.x;
        As[acb + 1][arow] = av.y;
        As[acb + 2][arow] = av.z;
        As[acb + 3][arow] = av.w;
        *(float4*)&Bs[brow][bcb] = bv;
        __syncthreads();
        #pragma unroll
        for (int kk = 0; kk < 8; kk++) {
            float a[8], bb[8];
            *(float4*)(a)      = *(const float4*)&As[kk][ty * 4];
            *(float4*)(a + 4)  = *(const float4*)&As[kk][64 + ty * 4];
            *(float4*)(bb)     = *(const float4*)&Bs[kk][tx * 4];
            *(float4*)(bb + 4) = *(const float4*)&Bs[kk][64 + tx * 4];
            #pragma unroll
            for (int i = 0; i < 8; i++)
                #pragma unroll
                for (int j = 0; j < 8; j++) acc[i][j] += a[i] * bb[j];
        }
    }

    #pragma unroll
    for (int i = 0; i < 8; i++) {
        int gm = m0 + ((i < 4) ? (ty * 4 + i) : (64 + ty * 4 + i - 4));
        if (gm >= m_valid) continue;
        float g = gtab[gm], bias = btab[gm];
        float* op = (float*)(uintptr_t)outp[gm] + (long)b * obstr[gm];
        float4 r0, r1;
        r0.x = acc[i][0] * g + bias; r0.y = acc[i][1] * g + bias;
        r0.z = acc[i][2] * g + bias; r0.w = acc[i][3] * g + bias;
        r1.x = acc[i][4] * g + bias; r1.y = acc[i][5] * g + bias;
        r1.z = acc[i][6] * g + bias; r1.w = acc[i][7] * g + bias;
        *(float4*)(op + n0 + tx * 4)      = r0;
        *(float4*)(op + n0 + 64 + tx * 4) = r1;
    }
}

// ---------------------------------------------------------------------------
// Naive attention pipeline (independent re-derivation, no LDS, no in-place).
// w[b,H,T,p] = SCALE * sum_d q[b,H,d,p] * ks[b,d, p with axis(p)->T]
// ---------------------------------------------------------------------------
__global__ __launch_bounds__(256) void logits_kernel(
    const float* __restrict__ q, const float* __restrict__ ks,
    float* __restrict__ w, int stride)
{
    const int bh = blockIdx.z, b = bh >> 3, H = bh & 7;
    const int T = blockIdx.y;
    const int p = blockIdx.x * 256 + threadIdx.x;
    const int ip = (p / stride) % 12;
    const int pT = p + (T - ip) * stride;
    const float* qp = q + ((long)(b * 256 + H * 32)) * W4 + p;
    const float* kp = ks + ((long)(b * 32)) * W4 + pT;
    float acc = 0.f;
    #pragma unroll
    for (int d = 0; d < 32; d++)
        acc += qp[(long)d * W4] * kp[(long)d * W4];
    w[((long)bh * 12 + T) * W4 + p] = acc * SCALE;
}

// softmax over the `stride` axis (12 entries, positions pbase + s*stride)
__global__ __launch_bounds__(256) void softmax_kernel(float* w, int stride)
{
    const int bh = blockIdx.z, T = blockIdx.y;
    const int r = blockIdx.x * 256 + threadIdx.x;
    if (r >= 1728) return;
    const long base = ((long)bh * 12 + T) * W4
                    + (long)(r / stride) * (stride * 12) + (r % stride);
    float v[12], m = -1e30f;
    #pragma unroll
    for (int s = 0; s < 12; s++) { v[s] = w[base + (long)s * stride]; m = fmaxf(m, v[s]); }
    float sum = 0.f;
    #pragma unroll
    for (int s = 0; s < 12; s++) { v[s] = __expf(v[s] - m); sum += v[s]; }
    const float inv = 1.f / sum;
    #pragma unroll
    for (int s = 0; s < 12; s++) w[base + (long)s * stride] = v[s] * inv;
}

// out[b,c,q] = sum_s in[b,c, q+(s-T)*stride] * w[b,H(c),T(q), q+(s-T)*stride]
__global__ __launch_bounds__(256) void apply_kernel(
    const float* __restrict__ in, const float* __restrict__ w,
    float* __restrict__ out, int stride)
{
    const long row = blockIdx.y;                 // b*512 + c
    const int  b = (int)(row >> 9), c = (int)(row & 511), H = c >> 6;
    const int  q = blockIdx.x * 256 + threadIdx.x;
    const int  T = (q / stride) % 12;
    const long ibase = row * W4 + q - T * stride;
    const long wbase = (((long)(b * 8 + H)) * 12 + T) * W4 + q - T * stride;
    float acc = 0.f;
    #pragma unroll
    for (int s = 0; s < 12; s++)
        acc += in[ibase + (long)s * stride] * w[wbase + (long)s * stride];
    out[row * W4 + q] = acc;
}

// M[b,H,X,p] = sum_K w3[b,H,K,p] * w4[b,H,X, p+(K-k(p))*12]
__global__ __launch_bounds__(256) void mbuild_kernel(
    const float* __restrict__ w3, const float* __restrict__ w4,
    float* __restrict__ Mw)
{
    const int bh = blockIdx.z, X = blockIdx.y;
    const int p = blockIdx.x * 256 + threadIdx.x;
    const int kp = (p / 12) % 12;
    const long b3 = ((long)bh * 12) * W4 + p;
    const long b4 = ((long)bh * 12 + X) * W4 + p - kp * 12;
    float acc = 0.f;
    #pragma unroll
    for (int K = 0; K < 12; K++)
        acc += w3[b3 + (long)K * W4] * w4[b4 + K * 12];
    Mw[((long)bh * 12 + X) * W4 + p] = acc;
}

// y[b,c,q] = sum_l A2[b,c, q-L+l] * M[b,H(c),L(q), q-L+l]   (L = q%12)
__global__ __launch_bounds__(256) void apply34_kernel(
    const float* __restrict__ A2, const float* __restrict__ Mw,
    float* __restrict__ y)
{
    const long row = blockIdx.y;
    const int  b = (int)(row >> 9), c = (int)(row & 511), H = c >> 6;
    const int  q = blockIdx.x * 256 + threadIdx.x;
    const int  L = q % 12;
    const long abase = row * W4 + q - L;
    const long mbase = (((long)(b * 8 + H)) * 12 + L) * W4 + q - L;
    float acc = 0.f;
    #pragma unroll
    for (int l = 0; l < 12; l++)
        acc += A2[abase + l] * Mw[mbase + l];
    y[row * W4 + q] = acc;
}

// y += depthwise 3-tap conv(v0)*g + b   (zero-padded)
__global__ __launch_bounds__(256) void pe_add_kernel(
    const float* __restrict__ v0, float* __restrict__ y,
    const float* __restrict__ pw, const float* __restrict__ pg,
    const float* __restrict__ pb)
{
    const long row = blockIdx.y;
    const int  p   = blockIdx.x * 256 + threadIdx.x;
    const int  c   = (int)(row % 512);
    const long f   = row * W4 + p;
    float x0 = (p > 0)      ? v0[f - 1] : 0.f;
    float x1 = v0[f];
    float x2 = (p < W4 - 1) ? v0[f + 1] : 0.f;
    float pe = (x0 * pw[c * 3 + 0] + x1 * pw[c * 3 + 1] + x2 * pw[c * 3 + 2]) * pg[c] + pb[c];
    y[f] += pe;
}

// ---------------------------------------------------------------------------
extern "C" void kernel_launch(void* const* d_in, const int* in_sizes, int n_in,
                              void* d_out, int out_size, void* d_ws, size_t ws_size,
                              hipStream_t stream) {
    const float* x      = (const float*)d_in[0];
    const float* qk1_w  = (const float*)d_in[1];
    const float* qk1_g  = (const float*)d_in[2];
    const float* qk1_b  = (const float*)d_in[3];
    const float* qk2_w  = (const float*)d_in[4];
    const float* qk2_g  = (const float*)d_in[5];
    const float* qk2_b  = (const float*)d_in[6];
    const float* v_w    = (const float*)d_in[7];
    const float* v_g    = (const float*)d_in[8];
    const float* v_b    = (const float*)d_in[9];
    const float* pe_w   = (const float*)d_in[10];
    const float* pe_g   = (const float*)d_in[11];
    const float* pe_b   = (const float*)d_in[12];
    const float* proj_w = (const float*)d_in[13];
    const float* proj_g = (const float*)d_in[14];
    const float* proj_b = (const float*)d_in[15];
    float* out = (float*)d_out;

    char* ws = (char*)d_ws;
    size_t off = 0;
    auto alloc = [&](size_t bytes) -> void* {
        void* p = ws + off;
        off += (bytes + 255) & ~(size_t)255;
        return p;
    };
    // small control tables FIRST
    ull*   wpA = (ull*)alloc(896 * 8);
    ull*   opA = (ull*)alloc(896 * 8);
    int*   bsA = (int*)alloc(896 * 4);
    float* gA  = (float*)alloc(896 * 4);
    float* bA  = (float*)alloc(896 * 4);
    ull*   wpB = (ull*)alloc(384 * 8);
    ull*   opB = (ull*)alloc(384 * 8);
    int*   bsB = (int*)alloc(384 * 4);
    float* gB  = (float*)alloc(384 * 4);
    float* bB  = (float*)alloc(384 * 4);
    ull*   wpP = (ull*)alloc(512 * 8);
    ull*   opP = (ull*)alloc(512 * 8);
    int*   bsP = (int*)alloc(512 * 4);
    float* gP  = (float*)alloc(512 * 4);
    float* bP  = (float*)alloc(512 * 4);
    float* ksw1 = (float*)alloc(32 * 512 * 4);
    float* ksw2 = (float*)alloc(32 * 512 * 4);
    // big buffers
    float* qbuf = (float*)alloc(4L * 256 * W4 * 4);   // q1, later q2 (85 MB)
    float* ks1  = (float*)alloc(4L * 32 * W4 * 4);    // 10.6 MB
    float* ks2  = (float*)alloc(4L * 32 * W4 * 4);    // 10.6 MB
    float* w1   = (float*)alloc(4L * 96 * W4 * 4);    // 31.9 MB  (b*8H*12T)
    float* w2   = (float*)alloc(4L * 96 * W4 * 4);
    float* w3   = (float*)alloc(4L * 96 * W4 * 4);
    float* w4   = (float*)alloc(4L * 96 * W4 * 4);
    float* Mw   = (float*)alloc(4L * 96 * W4 * 4);
    float* A1   = (float*)alloc(4L * 512 * W4 * 4);   // A1, then y (170 MB)
    float* A2   = (float*)alloc(4L * 512 * W4 * 4);   // 170 MB
    const size_t needed = off;                        // ~606 MB
    if (ws_size < needed) return;   // diagnostic: absmax stays 454.0 => ws too small

    // 1. fold + tables
    prep_kernel<<<67, 256, 0, stream>>>(
        qk1_w, qk1_g, qk1_b, qk2_w, qk2_g, qk2_b, v_w, v_g, v_b,
        proj_w, proj_g, proj_b, ksw1, ksw2,
        wpA, opA, bsA, gA, bA, wpB, opB, bsB, gB, bB, wpP, opP, bsP, gP, bP,
        qbuf, ks1, ks2, out, A1);

    // 2. GEMM-a: q1 -> qbuf, v0 -> d_out, k1sum -> ks1
    conv1x1_gemm<<<dim3(162, 7, 4), 256, 0, stream>>>(
        x, 512L * W4, wpA, opA, bsA, gA, bA, 512, 800);

    // 3. a1 weights (axis i, stride 1728)
    logits_kernel<<<dim3(81, 12, 32), 256, 0, stream>>>(qbuf, ks1, w1, 1728);
    softmax_kernel<<<dim3(7, 12, 32), 256, 0, stream>>>(w1, 1728);

    // 4. apply a1: A1 = sum_i v0 * a1
    apply_kernel<<<dim3(81, 2048), 256, 0, stream>>>(out, w1, A1, 1728);

    // 5. GEMM-b: q2 -> qbuf (q1 dead), k2sum -> ks2
    conv1x1_gemm<<<dim3(162, 3, 4), 256, 0, stream>>>(
        x, 512L * W4, wpB, opB, bsB, gB, bB, 512, 288);

    // 6. a2/a3/a4 weights (axes j/k/l, strides 144/12/1)
    logits_kernel<<<dim3(81, 12, 32), 256, 0, stream>>>(qbuf, ks2, w2, 144);
    logits_kernel<<<dim3(81, 12, 32), 256, 0, stream>>>(qbuf, ks2, w3, 12);
    logits_kernel<<<dim3(81, 12, 32), 256, 0, stream>>>(qbuf, ks2, w4, 1);
    softmax_kernel<<<dim3(7, 12, 32), 256, 0, stream>>>(w2, 144);
    softmax_kernel<<<dim3(7, 12, 32), 256, 0, stream>>>(w3, 12);
    softmax_kernel<<<dim3(7, 12, 32), 256, 0, stream>>>(w4, 1);

    // 7. M = sum_K a3*a4
    mbuild_kernel<<<dim3(81, 12, 32), 256, 0, stream>>>(w3, w4, Mw);

    // 8. apply a2: A2 = sum_j A1 * a2
    apply_kernel<<<dim3(81, 2048), 256, 0, stream>>>(A1, w2, A2, 144);

    // 9. y = sum_l A2 * M   (into A1 region, A1 dead)
    apply34_kernel<<<dim3(81, 2048), 256, 0, stream>>>(A2, Mw, A1);

    // 10. y += pe(v0)
    pe_add_kernel<<<dim3(81, 2048), 256, 0, stream>>>(out, A1, pe_w, pe_g, pe_b);

    // 11. proj: y -> d_out
    conv1x1_gemm<<<dim3(162, 4, 4), 256, 0, stream>>>(
        A1, 512L * W4, wpP, opP, bsP, gP, bP, 512, 512);
}

// Round 3
// 2166.484 us; speedup vs baseline: 1.7256x; 1.7256x over previous
//
#include <hip/hip_runtime.h>
#include <hip/hip_bf16.h>
#include <stdint.h>

#define W4   20736           // 12^4 positions (w == W4, no padding)
#define NH   8
#define KD   32
#define HD   64
#define C    512
#define SCALE 0.17677669529663687f   // 1/sqrt(32)

typedef unsigned long long ull;
typedef short bf16x8 __attribute__((ext_vector_type(8)));
typedef float f32x4 __attribute__((ext_vector_type(4)));

#define AS1(p) ((const __attribute__((address_space(1))) void*)(p))
#define AS3(p) ((__attribute__((address_space(3))) void*)(p))

// Manual RNE fp32 -> bf16 (no NaN handling needed; values finite)
static __device__ __forceinline__ unsigned short f2bf(float v) {
    unsigned u = __builtin_bit_cast(unsigned, v);
    unsigned r = u + 0x7FFF + ((u >> 16) & 1);
    return (unsigned short)(r >> 16);
}
static __device__ __forceinline__ float bf2f(unsigned short u) {
    unsigned x = ((unsigned)u) << 16;
    return __builtin_bit_cast(float, x);
}

// ---------------------------------------------------------------------------
// prep1: fold head-summed K weights (fp32); build epilogue routing tables.
// ---------------------------------------------------------------------------
__global__ __launch_bounds__(256) void prep1_kernel(
    const float* qk1_w, const float* qk1_g, const float* qk1_b,
    const float* qk2_w, const float* qk2_g, const float* qk2_b,
    const float* v_b,   const float* proj_b,
    float* ksw1, float* ksw2,
    ull* opA, int* bsA, float* biasA,
    ull* opP, int* bsP, float* biasP,
    float* q1buf, float* q2buf, float* ks1buf, float* ks2buf, float* vdst)
{
    int z = blockIdx.x, t = threadIdx.x;
    if (z < 32) {                       // ksw1 row d=z : sum_h g*W over k1 channels
        int d = z;
        for (int c = t; c < 512; c += 256) {
            float a = 0.f;
            #pragma unroll
            for (int h = 0; h < 8; h++) {
                int ch = h * 64 + 32 + d;
                a += qk1_g[ch] * qk1_w[ch * 512 + c];
            }
            ksw1[d * 512 + c] = a;
        }
    } else if (z < 64) {                // ksw2 row d=z-32
        int d = z - 32;
        for (int c = t; c < 512; c += 256) {
            float a = 0.f;
            #pragma unroll
            for (int h = 0; h < 8; h++) {
                int ch = h * 64 + 32 + d;
                a += qk2_g[ch] * qk2_w[ch * 512 + c];
            }
            ksw2[d * 512 + c] = a;
        }
    } else if (z == 64) {               // table A: 1152 rows (1088 valid)
        for (int o = t; o < 1152; o += 256) {
            ull op; int bs; float bb;
            if (o < 256) {
                int ch = (o >> 5) * 64 + (o & 31);
                bb = qk1_b[ch];
                op = (ull)(uintptr_t)(q1buf + (size_t)o * W4); bs = 256 * W4;
            } else if (o < 512) {
                int oo = o - 256, ch = (oo >> 5) * 64 + (oo & 31);
                bb = qk2_b[ch];
                op = (ull)(uintptr_t)(q2buf + (size_t)oo * W4); bs = 256 * W4;
            } else if (o < 1024) {
                int c = o - 512;
                bb = v_b[c];
                op = (ull)(uintptr_t)(vdst + (size_t)c * W4); bs = 512 * W4;
            } else if (o < 1056) {
                int d = o - 1024; bb = 0.f;
                #pragma unroll
                for (int h = 0; h < 8; h++) bb += qk1_b[h * 64 + 32 + d];
                op = (ull)(uintptr_t)(ks1buf + (size_t)d * W4); bs = 32 * W4;
            } else if (o < 1088) {
                int d = o - 1056; bb = 0.f;
                #pragma unroll
                for (int h = 0; h < 8; h++) bb += qk2_b[h * 64 + 32 + d];
                op = (ull)(uintptr_t)(ks2buf + (size_t)d * W4); bs = 32 * W4;
            } else {                    // pad (masked by m_valid in epilogue)
                bb = 0.f; op = (ull)(uintptr_t)q1buf; bs = 0;
            }
            opA[o] = op; bsA[o] = bs; biasA[o] = bb;
        }
    } else {                            // table P (proj, 512 rows)
        for (int o = t; o < 512; o += 256) {
            opP[o] = (ull)(uintptr_t)(vdst + (size_t)o * W4);
            bsP[o] = 512 * W4;
            biasP[o] = proj_b[o];
        }
    }
}

// ---------------------------------------------------------------------------
// prep2: build packed bf16 hi/lo weight planes (g folded into rows).
// rows 0..1151 -> Wa (q1|q2|v|ks1|ks2|pad0); rows 1152..1663 -> Wp (proj).
// ---------------------------------------------------------------------------
__global__ __launch_bounds__(256) void prep2_kernel(
    const float* qk1_w, const float* qk1_g,
    const float* qk2_w, const float* qk2_g,
    const float* v_w,   const float* v_g,
    const float* proj_w,const float* proj_g,
    const float* ksw1,  const float* ksw2,
    unsigned short* Wah, unsigned short* Wal,
    unsigned short* Wph, unsigned short* Wpl)
{
    int row = blockIdx.x, t = threadIdx.x;
    for (int c = t; c < 512; c += 256) {
        float wv;
        unsigned short *dh, *dl; int idx;
        if (row < 1152) {
            int o = row;
            if (o < 256) {
                int ch = (o >> 5) * 64 + (o & 31);
                wv = qk1_w[ch * 512 + c] * qk1_g[ch];
            } else if (o < 512) {
                int oo = o - 256, ch = (oo >> 5) * 64 + (oo & 31);
                wv = qk2_w[ch * 512 + c] * qk2_g[ch];
            } else if (o < 1024) {
                int cc = o - 512;
                wv = v_w[cc * 512 + c] * v_g[cc];
            } else if (o < 1056) {
                wv = ksw1[(o - 1024) * 512 + c];
            } else if (o < 1088) {
                wv = ksw2[(o - 1056) * 512 + c];
            } else wv = 0.f;
            dh = Wah; dl = Wal; idx = o * 512 + c;
        } else {
            int o = row - 1152;
            wv = proj_w[o * 512 + c] * proj_g[o];
            dh = Wph; dl = Wpl; idx = o * 512 + c;
        }
        unsigned short h = f2bf(wv);
        dh[idx] = h;
        dl[idx] = f2bf(wv - bf2f(h));
    }
}

// ---------------------------------------------------------------------------
// castT: fp32 [b][512][W4] -> bf16 hi/lo [b][W4][512] (transposed, split).
// 32x32 LDS tile transpose. Grid (648, 16, 4), block 256.
// ---------------------------------------------------------------------------
__global__ __launch_bounds__(256) void castT_kernel(
    const float* __restrict__ in,
    unsigned short* __restrict__ oh, unsigned short* __restrict__ ol)
{
    __shared__ float tile[32][33];
    const int p0 = blockIdx.x * 32, c0 = blockIdx.y * 32, b = blockIdx.z;
    const int tx = threadIdx.x & 31, ty = threadIdx.x >> 5;
    const float* ip = in + ((long)b * 512 + c0) * W4 + p0;
    #pragma unroll
    for (int r = 0; r < 4; r++)
        tile[ty + r * 8][tx] = ip[(long)(ty + r * 8) * W4 + tx];
    __syncthreads();
    unsigned short* ohp = oh + ((long)b * W4 + p0) * 512 + c0;
    unsigned short* olp = ol + ((long)b * W4 + p0) * 512 + c0;
    #pragma unroll
    for (int r = 0; r < 4; r++) {
        float v = tile[tx][ty + r * 8];
        unsigned short h = f2bf(v);
        ohp[(long)(ty + r * 8) * 512 + tx] = h;
        olp[(long)(ty + r * 8) * 512 + tx] = f2bf(v - bf2f(h));
    }
}

// ---------------------------------------------------------------------------
// mfma_gemm: out[o,p] = A[o,:]·B[p,:] + bias[o], split-bf16 (3 MFMA / tile).
// A: [M][512] bf16 planes; B: [b][W4][512] bf16 planes (p-major = x^T).
// 128x128 tile, BK=32, 256 thr = 4 waves (2x2), 16x16x32 MFMA, m97 staging.
// Epilogue routes each output row via opX/bsX tables.
// ---------------------------------------------------------------------------
__global__ __launch_bounds__(256, 2) void mfma_gemm(
    const unsigned short* __restrict__ Ah, const unsigned short* __restrict__ Al,
    const unsigned short* __restrict__ Bh, const unsigned short* __restrict__ Bl,
    const ull* __restrict__ outp, const int* __restrict__ obstr,
    const float* __restrict__ btab, int m_valid)
{
    __shared__ unsigned short sAh[4096], sAl[4096], sBh[4096], sBl[4096];
    const int t = threadIdx.x;
    const int m0 = blockIdx.x * 128;
    const int p0 = blockIdx.y * 128;
    const int b  = blockIdx.z;
    const int lane = t & 63, wid = t >> 6;
    const int wm = wid >> 1, wn = wid & 1;
    // staging: slot t covers LDS bytes [t*16, t*16+16); row = t>>2, part = t&3
    const int r0 = t >> 2, part = (t & 3) * 8;
    const unsigned short* gAh = Ah + (size_t)(m0 + r0) * 512 + part;
    const unsigned short* gAl = Al + (size_t)(m0 + r0) * 512 + part;
    const unsigned short* gBh = Bh + ((size_t)b * W4 + p0 + r0) * 512 + part;
    const unsigned short* gBl = Bl + ((size_t)b * W4 + p0 + r0) * 512 + part;

    f32x4 acc[4][4];
    #pragma unroll
    for (int i = 0; i < 4; i++)
        #pragma unroll
        for (int j = 0; j < 4; j++) acc[i][j] = (f32x4)(0.f);

    const int arow = wm * 64 + (lane & 15);
    const int brow = wn * 64 + (lane & 15);
    const int koff = (lane >> 4) * 8;

    for (int k0 = 0; k0 < 512; k0 += 32) {
        __builtin_amdgcn_global_load_lds(AS1(gAh + k0),          AS3((char*)sAh + t * 16),        16, 0, 0);
        __builtin_amdgcn_global_load_lds(AS1(gAh + 32768 + k0),  AS3((char*)sAh + t * 16 + 4096), 16, 0, 0);
        __builtin_amdgcn_global_load_lds(AS1(gAl + k0),          AS3((char*)sAl + t * 16),        16, 0, 0);
        __builtin_amdgcn_global_load_lds(AS1(gAl + 32768 + k0),  AS3((char*)sAl + t * 16 + 4096), 16, 0, 0);
        __builtin_amdgcn_global_load_lds(AS1(gBh + k0),          AS3((char*)sBh + t * 16),        16, 0, 0);
        __builtin_amdgcn_global_load_lds(AS1(gBh + 32768 + k0),  AS3((char*)sBh + t * 16 + 4096), 16, 0, 0);
        __builtin_amdgcn_global_load_lds(AS1(gBl + k0),          AS3((char*)sBl + t * 16),        16, 0, 0);
        __builtin_amdgcn_global_load_lds(AS1(gBl + 32768 + k0),  AS3((char*)sBl + t * 16 + 4096), 16, 0, 0);
        __syncthreads();
        bf16x8 ah[4], al[4], bh[4], bl[4];
        #pragma unroll
        for (int f = 0; f < 4; f++) {
            ah[f] = *(const bf16x8*)(sAh + (arow + f * 16) * 32 + koff);
            al[f] = *(const bf16x8*)(sAl + (arow + f * 16) * 32 + koff);
            bh[f] = *(const bf16x8*)(sBh + (brow + f * 16) * 32 + koff);
            bl[f] = *(const bf16x8*)(sBl + (brow + f * 16) * 32 + koff);
        }
        #pragma unroll
        for (int i = 0; i < 4; i++)
            #pragma unroll
            for (int j = 0; j < 4; j++) {
                acc[i][j] = __builtin_amdgcn_mfma_f32_16x16x32_bf16(ah[i], bh[j], acc[i][j], 0, 0, 0);
                acc[i][j] = __builtin_amdgcn_mfma_f32_16x16x32_bf16(ah[i], bl[j], acc[i][j], 0, 0, 0);
                acc[i][j] = __builtin_amdgcn_mfma_f32_16x16x32_bf16(al[i], bh[j], acc[i][j], 0, 0, 0);
            }
        __syncthreads();
    }
    // epilogue: C/D layout col=lane&15 (p), row=(lane>>4)*4+reg (o)
    const int quad = lane >> 4, col = lane & 15;
    #pragma unroll
    for (int i = 0; i < 4; i++) {
        #pragma unroll
        for (int r = 0; r < 4; r++) {
            int o = m0 + wm * 64 + i * 16 + quad * 4 + r;
            if (o >= m_valid) continue;
            float bias = btab[o];
            float* op = (float*)(uintptr_t)outp[o] + (long)b * obstr[o] + p0 + wn * 64 + col;
            #pragma unroll
            for (int j = 0; j < 4; j++)
                op[j * 16] = acc[i][j][r] + bias;
        }
    }
}

// ---------------------------------------------------------------------------
// logits12: all 12 T per thread (q read once).
// w[b,H,T,p] = SCALE * sum_d q[b,H,d,p] * ks[b,d, pb + T*stride]
// ---------------------------------------------------------------------------
__global__ __launch_bounds__(256) void logits12_kernel(
    const float* __restrict__ q, const float* __restrict__ ks,
    float* __restrict__ w, int stride)
{
    const int bh = blockIdx.y, b = bh >> 3, H = bh & 7;
    const int p = blockIdx.x * 256 + threadIdx.x;
    const int ip = (p / stride) % 12;
    const float* qp = q + ((long)(b * 256 + H * 32)) * W4 + p;
    const float* kp = ks + ((long)(b * 32)) * W4 + p - (long)ip * stride;
    float acc[12];
    #pragma unroll
    for (int T = 0; T < 12; T++) acc[T] = 0.f;
    for (int d = 0; d < 32; d++) {
        float qv = qp[(long)d * W4];
        #pragma unroll
        for (int T = 0; T < 12; T++)
            acc[T] += qv * kp[(long)d * W4 + (long)T * stride];
    }
    #pragma unroll
    for (int T = 0; T < 12; T++)
        w[((long)bh * 12 + T) * W4 + p] = acc[T] * SCALE;
}

// softmax over the `stride` axis (12 entries) — verified round 2
__global__ __launch_bounds__(256) void softmax_kernel(float* w, int stride)
{
    const int bh = blockIdx.z, T = blockIdx.y;
    const int r = blockIdx.x * 256 + threadIdx.x;
    if (r >= 1728) return;
    const long base = ((long)bh * 12 + T) * W4
                    + (long)(r / stride) * (stride * 12) + (r % stride);
    float v[12], m = -1e30f;
    #pragma unroll
    for (int s = 0; s < 12; s++) { v[s] = w[base + (long)s * stride]; m = fmaxf(m, v[s]); }
    float sum = 0.f;
    #pragma unroll
    for (int s = 0; s < 12; s++) { v[s] = __expf(v[s] - m); sum += v[s]; }
    const float inv = 1.f / sum;
    #pragma unroll
    for (int s = 0; s < 12; s++) w[base + (long)s * stride] = v[s] * inv;
}

// out[b,c,q] = sum_s in[b,c,q+(s-T)*stride] * w[b,H,T,q+(s-T)*stride] — verified
__global__ __launch_bounds__(256) void apply_kernel(
    const float* __restrict__ in, const float* __restrict__ w,
    float* __restrict__ out, int stride)
{
    const long row = blockIdx.y;
    const int  b = (int)(row >> 9), c = (int)(row & 511), H = c >> 6;
    const int  q = blockIdx.x * 256 + threadIdx.x;
    const int  T = (q / stride) % 12;
    const long ibase = row * W4 + q - T * stride;
    const long wbase = (((long)(b * 8 + H)) * 12 + T) * W4 + q - T * stride;
    float acc = 0.f;
    #pragma unroll
    for (int s = 0; s < 12; s++)
        acc += in[ibase + (long)s * stride] * w[wbase + (long)s * stride];
    out[row * W4 + q] = acc;
}

// M[b,H,X,p] = sum_K w3[b,H,K,p] * w4[b,H,X, p+(K-k(p))*12] — verified
__global__ __launch_bounds__(256) void mbuild_kernel(
    const float* __restrict__ w3, const float* __restrict__ w4,
    float* __restrict__ Mw)
{
    const int bh = blockIdx.z, X = blockIdx.y;
    const int p = blockIdx.x * 256 + threadIdx.x;
    const int kp = (p / 12) % 12;
    const long b3 = ((long)bh * 12) * W4 + p;
    const long b4 = ((long)bh * 12 + X) * W4 + p - kp * 12;
    float acc = 0.f;
    #pragma unroll
    for (int K = 0; K < 12; K++)
        acc += w3[b3 + (long)K * W4] * w4[b4 + K * 12];
    Mw[((long)bh * 12 + X) * W4 + p] = acc;
}

// y[b,c,q] = sum_l A2[b,c,q-L+l] * M[b,H,L(q), q-L+l] — verified
__global__ __launch_bounds__(256) void apply34_kernel(
    const float* __restrict__ A2, const float* __restrict__ Mw,
    float* __restrict__ y)
{
    const long row = blockIdx.y;
    const int  b = (int)(row >> 9), c = (int)(row & 511), H = c >> 6;
    const int  q = blockIdx.x * 256 + threadIdx.x;
    const int  L = q % 12;
    const long abase = row * W4 + q - L;
    const long mbase = (((long)(b * 8 + H)) * 12 + L) * W4 + q - L;
    float acc = 0.f;
    #pragma unroll
    for (int l = 0; l < 12; l++)
        acc += A2[abase + l] * Mw[mbase + l];
    y[row * W4 + q] = acc;
}

// y += depthwise 3-tap conv(v0)*g + b — verified
__global__ __launch_bounds__(256) void pe_add_kernel(
    const float* __restrict__ v0, float* __restrict__ y,
    const float* __restrict__ pw, const float* __restrict__ pg,
    const float* __restrict__ pb)
{
    const long row = blockIdx.y;
    const int  p   = blockIdx.x * 256 + threadIdx.x;
    const int  c   = (int)(row % 512);
    const long f   = row * W4 + p;
    float x0 = (p > 0)      ? v0[f - 1] : 0.f;
    float x1 = v0[f];
    float x2 = (p < W4 - 1) ? v0[f + 1] : 0.f;
    float pe = (x0 * pw[c * 3 + 0] + x1 * pw[c * 3 + 1] + x2 * pw[c * 3 + 2]) * pg[c] + pb[c];
    y[f] += pe;
}

// ---------------------------------------------------------------------------
extern "C" void kernel_launch(void* const* d_in, const int* in_sizes, int n_in,
                              void* d_out, int out_size, void* d_ws, size_t ws_size,
                              hipStream_t stream) {
    const float* x      = (const float*)d_in[0];
    const float* qk1_w  = (const float*)d_in[1];
    const float* qk1_g  = (const float*)d_in[2];
    const float* qk1_b  = (const float*)d_in[3];
    const float* qk2_w  = (const float*)d_in[4];
    const float* qk2_g  = (const float*)d_in[5];
    const float* qk2_b  = (const float*)d_in[6];
    const float* v_w    = (const float*)d_in[7];
    const float* v_g    = (const float*)d_in[8];
    const float* v_b    = (const float*)d_in[9];
    const float* pe_w   = (const float*)d_in[10];
    const float* pe_g   = (const float*)d_in[11];
    const float* pe_b   = (const float*)d_in[12];
    const float* proj_w = (const float*)d_in[13];
    const float* proj_g = (const float*)d_in[14];
    const float* proj_b = (const float*)d_in[15];
    float* out = (float*)d_out;

    char* ws = (char*)d_ws;
    size_t off = 0;
    auto alloc = [&](size_t bytes) -> void* {
        void* p = ws + off;
        off += (bytes + 255) & ~(size_t)255;
        return p;
    };
    const size_t QSZ = 4L * 256 * W4 * 4;   // 84,934,656 (also = one xT plane)
    const size_t KSZ = 4L * 32 * W4 * 4;    // 10,616,832
    const size_t WSZ = 4L * 96 * W4 * 4;    // 31,850,496
    const size_t ASZ = 4L * 512 * W4 * 4;   // 169,869,312

    ull*   opA   = (ull*)alloc(1152 * 8);
    int*   bsA   = (int*)alloc(1152 * 4);
    float* biasA = (float*)alloc(1152 * 4);
    ull*   opP   = (ull*)alloc(512 * 8);
    int*   bsP   = (int*)alloc(512 * 4);
    float* biasP = (float*)alloc(512 * 4);
    float* ksw1  = (float*)alloc(32 * 512 * 4);
    float* ksw2  = (float*)alloc(32 * 512 * 4);
    unsigned short* Wah = (unsigned short*)alloc(1152 * 512 * 2);
    unsigned short* Wal = (unsigned short*)alloc(1152 * 512 * 2);
    unsigned short* Wph = (unsigned short*)alloc(512 * 512 * 2);
    unsigned short* Wpl = (unsigned short*)alloc(512 * 512 * 2);
    char*  RX  = (char*)alloc(2 * QSZ);     // xT planes / w2,w3,w4 / yT planes
    char*  RQ  = (char*)alloc(2 * QSZ);     // q1,q2 / A2
    float* ks1 = (float*)alloc(KSZ);
    float* ks2 = (float*)alloc(KSZ);
    float* w1  = (float*)alloc(WSZ);        // w1, later Mw
    float* A1  = (float*)alloc(ASZ);
    if (ws_size < off) return;              // ws known >= 606 MB; we use ~540 MB

    // region aliases (stream-ordered lifetimes; see launch sequence)
    unsigned short* xTh = (unsigned short*)RX;
    unsigned short* xTl = (unsigned short*)(RX + QSZ);
    float* w2 = (float*)RX;                 // written after xT is dead
    float* w3 = (float*)(RX + WSZ);
    float* w4 = (float*)(RX + 2 * WSZ);
    unsigned short* yTh = (unsigned short*)RX;  // written after w2-4 dead
    unsigned short* yTl = (unsigned short*)(RX + QSZ);
    float* q1 = (float*)RQ;
    float* q2 = (float*)(RQ + QSZ);
    float* A2 = (float*)RQ;                 // written after q1,q2 dead
    float* Mw = w1;                         // written after w1 dead

    // 1. tables + k-weight folds (fp32)
    prep1_kernel<<<66, 256, 0, stream>>>(
        qk1_w, qk1_g, qk1_b, qk2_w, qk2_g, qk2_b, v_b, proj_b,
        ksw1, ksw2, opA, bsA, biasA, opP, bsP, biasP,
        q1, q2, ks1, ks2, out);

    // 2. packed bf16 hi/lo weight planes (needs ksw from prep1)
    prep2_kernel<<<1664, 256, 0, stream>>>(
        qk1_w, qk1_g, qk2_w, qk2_g, v_w, v_g, proj_w, proj_g,
        ksw1, ksw2, Wah, Wal, Wph, Wpl);

    // 3. x -> x^T bf16 hi/lo planes
    castT_kernel<<<dim3(648, 16, 4), 256, 0, stream>>>(x, xTh, xTl);

    // 4. fused QKV GEMM (split-bf16 MFMA): q1,q2,v0(d_out),ks1,ks2
    mfma_gemm<<<dim3(9, 162, 4), 256, 0, stream>>>(
        Wah, Wal, xTh, xTl, opA, bsA, biasA, 1088);

    // 5. a1 weights (axis i, stride 1728) + softmax
    logits12_kernel<<<dim3(81, 32), 256, 0, stream>>>(q1, ks1, w1, 1728);
    softmax_kernel<<<dim3(7, 12, 32), 256, 0, stream>>>(w1, 1728);

    // 6. apply a1: A1 = v0 (x) w1
    apply_kernel<<<dim3(81, 2048), 256, 0, stream>>>(out, w1, A1, 1728);

    // 7. a2/a3/a4 weights (axes j/k/l) + softmaxes
    logits12_kernel<<<dim3(81, 32), 256, 0, stream>>>(q2, ks2, w2, 144);
    logits12_kernel<<<dim3(81, 32), 256, 0, stream>>>(q2, ks2, w3, 12);
    logits12_kernel<<<dim3(81, 32), 256, 0, stream>>>(q2, ks2, w4, 1);
    softmax_kernel<<<dim3(7, 12, 32), 256, 0, stream>>>(w2, 144);
    softmax_kernel<<<dim3(7, 12, 32), 256, 0, stream>>>(w3, 12);
    softmax_kernel<<<dim3(7, 12, 32), 256, 0, stream>>>(w4, 1);

    // 8. M = sum_K a3*a4
    mbuild_kernel<<<dim3(81, 12, 32), 256, 0, stream>>>(w3, w4, Mw);

    // 9. apply a2: A2 = A1 (x) w2
    apply_kernel<<<dim3(81, 2048), 256, 0, stream>>>(A1, w2, A2, 144);

    // 10. y = A2 (x) M  (into A1)
    apply34_kernel<<<dim3(81, 2048), 256, 0, stream>>>(A2, Mw, A1);

    // 11. y += pe(v0)
    pe_add_kernel<<<dim3(81, 2048), 256, 0, stream>>>(out, A1, pe_w, pe_g, pe_b);

    // 12. y -> y^T bf16 hi/lo planes
    castT_kernel<<<dim3(648, 16, 4), 256, 0, stream>>>(A1, yTh, yTl);

    // 13. proj GEMM -> d_out
    mfma_gemm<<<dim3(4, 162, 4), 256, 0, stream>>>(
        Wph, Wpl, yTh, yTl, opP, bsP, biasP, 512);
}